// Round 1
// baseline (11342.297 us; speedup 1.0000x reference)
//
#include <hip/hip_runtime.h>
#include <hip/hip_bf16.h>

typedef __attribute__((ext_vector_type(8))) short bf16x8;
typedef __attribute__((ext_vector_type(4))) float f32x4;

static __device__ __forceinline__ unsigned short f2bf(float f) {
    union { float f; unsigned u; } v; v.f = f;
    unsigned r = v.u + 0x7FFF + ((v.u >> 16) & 1);
    return (unsigned short)(r >> 16);
}
static __device__ __forceinline__ float bf2f(unsigned short h) {
    union { unsigned u; float f; } v; v.u = ((unsigned)h) << 16;
    return v.f;
}

// ---- convert f32 -> bf16 (4 elems/thread) ----
__global__ __launch_bounds__(256) void cvt_bf16(const float* __restrict__ x,
                                                unsigned short* __restrict__ out, int n4) {
    int i = blockIdx.x * 256 + threadIdx.x;
    if (i >= n4) return;
    float4 v = ((const float4*)x)[i];
    ushort4 o;
    o.x = f2bf(v.x); o.y = f2bf(v.y); o.z = f2bf(v.z); o.w = f2bf(v.w);
    ((ushort4*)out)[i] = o;
}

// ---- relu + convert f32 -> bf16 ----
__global__ __launch_bounds__(256) void relu_cvt_bf16(const float* __restrict__ x,
                                                     unsigned short* __restrict__ out, int n4) {
    int i = blockIdx.x * 256 + threadIdx.x;
    if (i >= n4) return;
    float4 v = ((const float4*)x)[i];
    ushort4 o;
    o.x = f2bf(fmaxf(v.x, 0.f)); o.y = f2bf(fmaxf(v.y, 0.f));
    o.z = f2bf(fmaxf(v.z, 0.f)); o.w = f2bf(fmaxf(v.w, 0.f));
    ((ushort4*)out)[i] = o;
}

// ---- build swizzled B = [W_rel | W_root] in MFMA B-fragment order ----
// layout: bsw[((kt*16+ct)*64 + L)*8 + j] = B[kt*32+(L>>4)*8+j][ct*16+(L&15)]
__global__ __launch_bounds__(256) void build_bsw(const float* __restrict__ Wrel,
                                                 const float* __restrict__ Wroot,
                                                 unsigned short* __restrict__ bsw) {
    int idx = blockIdx.x * 256 + threadIdx.x;  // 32768 total
    int j = idx & 7, L = (idx >> 3) & 63, ct = (idx >> 9) & 15, kt = idx >> 13;
    int k = kt * 32 + ((L >> 4) * 8) + j;
    int c = ct * 16 + (L & 15);
    float v = (c < 128) ? Wrel[k * 128 + c] : Wroot[k * 128 + (c - 128)];
    bsw[idx] = f2bf(v);
}

// ---- build swizzled W_lin [256,40] padded to 48 cols ----
__global__ __launch_bounds__(256) void build_bswL(const float* __restrict__ Wlin,
                                                  unsigned short* __restrict__ bsw, int total) {
    int idx = blockIdx.x * 256 + threadIdx.x;  // 12288 total
    if (idx >= total) return;
    int t = idx;
    int j = t & 7; t >>= 3;
    int L = t & 63; t >>= 6;
    int ct = t % 3;
    int kt = t / 3;
    int k = kt * 32 + ((L >> 4) * 8) + j;
    int c = ct * 16 + (L & 15);
    float v = (c < 40) ? Wlin[k * 40 + c] : 0.f;
    bsw[idx] = f2bf(v);
}

// ---- layer GEMM: [N,128]bf16 @ [128,256]bf16 -> xr[N,128]bf16 (cols 0..127),
//      acc[N,128]f32 = cols 128..255 + bias ----
__global__ __launch_bounds__(256) void gemm_layer(const unsigned short* __restrict__ Abf,
                                                  const unsigned short* __restrict__ Bsw,
                                                  const float* __restrict__ bias,
                                                  unsigned short* __restrict__ xr,
                                                  float* __restrict__ accbuf, int N) {
    int wid = blockIdx.x * 4 + (threadIdx.x >> 6);
    int L = threadIdx.x & 63;
    int r0 = wid * 16;
    if (r0 >= N) return;
    int arow = r0 + (L & 15);
    const bf16x8* Aptr = (const bf16x8*)(Abf + (size_t)arow * 128 + ((L >> 4) * 8));
    const bf16x8* Bptr = ((const bf16x8*)Bsw) + L;
    f32x4 acc[16];
#pragma unroll
    for (int i = 0; i < 16; i++) acc[i] = (f32x4){0.f, 0.f, 0.f, 0.f};
#pragma unroll
    for (int kt = 0; kt < 4; kt++) {
        bf16x8 a = Aptr[kt * 4];  // advance 32 bf16 per k-step
#pragma unroll
        for (int ct = 0; ct < 16; ct++) {
            bf16x8 b = Bptr[(kt * 16 + ct) * 64];
            acc[ct] = __builtin_amdgcn_mfma_f32_16x16x32_bf16(a, b, acc[ct], 0, 0, 0);
        }
    }
    int rbase = r0 + (L >> 4) * 4;
    int cl = L & 15;
#pragma unroll
    for (int ct = 0; ct < 16; ct++) {
        int col = ct * 16 + cl;
#pragma unroll
        for (int r = 0; r < 4; r++) {
            int row = rbase + r;
            float v = acc[ct][r];
            if (col < 128)
                xr[(size_t)row * 128 + col] = f2bf(v);
            else
                accbuf[(size_t)row * 128 + (col - 128)] = v + bias[col - 128];
        }
    }
}

// ---- edge scatter: acc[dst] += xr[src]  (16 threads/edge, 8 feats each) ----
__global__ __launch_bounds__(256) void scatter_add(const unsigned short* __restrict__ xr,
                                                   float* __restrict__ accbuf,
                                                   const int* __restrict__ src,
                                                   const int* __restrict__ dst, int E) {
    int tid = blockIdx.x * 256 + threadIdx.x;
    int e = tid >> 4;
    if (e >= E) return;
    int lane = tid & 15;
    int s = src[e], d = dst[e];
    bf16x8 v8 = *((const bf16x8*)(xr + (size_t)s * 128 + lane * 8));
    float* out = accbuf + (size_t)d * 128 + lane * 8;
#pragma unroll
    for (int j = 0; j < 8; j++) {
        unsafeAtomicAdd(out + j, bf2f((unsigned short)v8[j]));
    }
}

// ---- final GEMM: [x1|x2] (K=256) @ W_lin(pad48) + b_lin -> logits[N,40] f32 ----
__global__ __launch_bounds__(256) void gemm_final(const unsigned short* __restrict__ x1bf,
                                                  const unsigned short* __restrict__ x2bf,
                                                  const unsigned short* __restrict__ Bsw,
                                                  const float* __restrict__ blin,
                                                  float* __restrict__ logits, int N) {
    int wid = blockIdx.x * 4 + (threadIdx.x >> 6);
    int L = threadIdx.x & 63;
    int r0 = wid * 16;
    if (r0 >= N) return;
    int arow = r0 + (L & 15);
    f32x4 acc[3];
#pragma unroll
    for (int i = 0; i < 3; i++) acc[i] = (f32x4){0.f, 0.f, 0.f, 0.f};
#pragma unroll
    for (int kt = 0; kt < 8; kt++) {
        const unsigned short* Ab = (kt < 4) ? x1bf : x2bf;
        int kk = (kt & 3) * 32 + ((L >> 4) * 8);
        bf16x8 a = *((const bf16x8*)(Ab + (size_t)arow * 128 + kk));
#pragma unroll
        for (int ct = 0; ct < 3; ct++) {
            bf16x8 b = ((const bf16x8*)Bsw)[(kt * 3 + ct) * 64 + L];
            acc[ct] = __builtin_amdgcn_mfma_f32_16x16x32_bf16(a, b, acc[ct], 0, 0, 0);
        }
    }
    int rbase = r0 + (L >> 4) * 4;
    int cl = L & 15;
#pragma unroll
    for (int ct = 0; ct < 3; ct++) {
        int col = ct * 16 + cl;
        if (col < 40) {
#pragma unroll
            for (int r = 0; r < 4; r++) {
                logits[(size_t)(rbase + r) * 40 + col] = acc[ct][r] + blin[col];
            }
        }
    }
}

// ---- row-wise log_softmax over 40 classes, one wave per node ----
__global__ __launch_bounds__(256) void log_softmax_k(const float* __restrict__ logits,
                                                     float* __restrict__ out, int N) {
    int node = blockIdx.x * 4 + (threadIdx.x >> 6);
    if (node >= N) return;
    int L = threadIdx.x & 63;
    float v = (L < 40) ? logits[(size_t)node * 40 + L] : -__builtin_inff();
    float m = v;
#pragma unroll
    for (int off = 32; off >= 1; off >>= 1) m = fmaxf(m, __shfl_xor(m, off, 64));
    float e = (L < 40) ? __expf(v - m) : 0.f;
    float s = e;
#pragma unroll
    for (int off = 32; off >= 1; off >>= 1) s += __shfl_xor(s, off, 64);
    if (L < 40) out[(size_t)node * 40 + L] = v - m - __logf(s);
}

extern "C" void kernel_launch(void* const* d_in, const int* in_sizes, int n_in,
                              void* d_out, int out_size, void* d_ws, size_t ws_size,
                              hipStream_t stream) {
    const float* x      = (const float*)d_in[0];
    const int*   edge   = (const int*)d_in[1];
    const float* Wrel1  = (const float*)d_in[2];
    const float* brel1  = (const float*)d_in[3];
    const float* Wroot1 = (const float*)d_in[4];
    const float* Wrel2  = (const float*)d_in[5];
    const float* brel2  = (const float*)d_in[6];
    const float* Wroot2 = (const float*)d_in[7];
    const float* Wlin   = (const float*)d_in[8];
    const float* blin   = (const float*)d_in[9];

    const int N = in_sizes[0] / 128;
    const int E = in_sizes[1] / 2;
    const int* src = edge;
    const int* dst = edge + E;

    // workspace layout (aliased where lifetimes permit)
    char* ws = (char*)d_ws;
    size_t off = 0;
    auto alloc = [&](size_t bytes) -> void* {
        void* p = ws + off;
        off += (bytes + 255) & ~(size_t)255;
        return p;
    };
    unsigned short* xbf  = (unsigned short*)alloc((size_t)N * 128 * 2);  // also reused as x2bf
    unsigned short* x1bf = (unsigned short*)alloc((size_t)N * 128 * 2);
    unsigned short* xr   = (unsigned short*)alloc((size_t)N * 128 * 2);
    float* acc1          = (float*)alloc((size_t)N * 128 * 4);           // reused as logits
    float* acc2          = (float*)alloc((size_t)N * 128 * 4);
    unsigned short* bsw1 = (unsigned short*)alloc(32768 * 2);
    unsigned short* bsw2 = (unsigned short*)alloc(32768 * 2);
    unsigned short* bswL = (unsigned short*)alloc(12288 * 2);
    unsigned short* x2bf = xbf;
    float* logits        = acc1;

    const int n4 = (N * 128) / 4;
    const int cvtBlocks = (n4 + 255) / 256;
    const int rowTiles = (N + 15) / 16;
    const int gemmBlocks = (rowTiles + 3) / 4;
    const int scatBlocks = (int)(((long long)E * 16 + 255) / 256);

    build_bsw<<<128, 256, 0, stream>>>(Wrel1, Wroot1, bsw1);
    build_bsw<<<128, 256, 0, stream>>>(Wrel2, Wroot2, bsw2);
    build_bswL<<<48, 256, 0, stream>>>(Wlin, bswL, 12288);

    cvt_bf16<<<cvtBlocks, 256, 0, stream>>>(x, xbf, n4);

    // layer 1
    gemm_layer<<<gemmBlocks, 256, 0, stream>>>(xbf, bsw1, brel1, xr, acc1, N);
    scatter_add<<<scatBlocks, 256, 0, stream>>>(xr, acc1, src, dst, E);
    relu_cvt_bf16<<<cvtBlocks, 256, 0, stream>>>(acc1, x1bf, n4);

    // layer 2
    gemm_layer<<<gemmBlocks, 256, 0, stream>>>(x1bf, bsw2, brel2, xr, acc2, N);
    scatter_add<<<scatBlocks, 256, 0, stream>>>(xr, acc2, src, dst, E);
    relu_cvt_bf16<<<cvtBlocks, 256, 0, stream>>>(acc2, x2bf, n4);

    // classifier + log_softmax
    gemm_final<<<gemmBlocks, 256, 0, stream>>>(x1bf, x2bf, bswL, blin, logits, N);
    log_softmax_k<<<(N + 3) / 4, 256, 0, stream>>>(logits, (float*)d_out, N);
}

// Round 2
// 613.365 us; speedup vs baseline: 18.4919x; 18.4919x over previous
//
#include <hip/hip_runtime.h>
#include <hip/hip_bf16.h>

typedef __attribute__((ext_vector_type(8))) short bf16x8;
typedef __attribute__((ext_vector_type(4))) float f32x4;

static __device__ __forceinline__ unsigned short f2bf(float f) {
    union { float f; unsigned u; } v; v.f = f;
    unsigned r = v.u + 0x7FFF + ((v.u >> 16) & 1);
    return (unsigned short)(r >> 16);
}
static __device__ __forceinline__ float bf2f(unsigned short h) {
    union { unsigned u; float f; } v; v.u = ((unsigned)h) << 16;
    return v.f;
}

// ---- convert f32 -> bf16 (4 elems/thread) ----
__global__ __launch_bounds__(256) void cvt_bf16(const float* __restrict__ x,
                                                unsigned short* __restrict__ out, int n4) {
    int i = blockIdx.x * 256 + threadIdx.x;
    if (i >= n4) return;
    float4 v = ((const float4*)x)[i];
    ushort4 o;
    o.x = f2bf(v.x); o.y = f2bf(v.y); o.z = f2bf(v.z); o.w = f2bf(v.w);
    ((ushort4*)out)[i] = o;
}

// ---- build swizzled B = [W_rel | W_root] in MFMA B-fragment order ----
__global__ __launch_bounds__(256) void build_bsw(const float* __restrict__ Wrel,
                                                 const float* __restrict__ Wroot,
                                                 unsigned short* __restrict__ bsw) {
    int idx = blockIdx.x * 256 + threadIdx.x;  // 32768 total
    int j = idx & 7, L = (idx >> 3) & 63, ct = (idx >> 9) & 15, kt = idx >> 13;
    int k = kt * 32 + ((L >> 4) * 8) + j;
    int c = ct * 16 + (L & 15);
    float v = (c < 128) ? Wrel[k * 128 + c] : Wroot[k * 128 + (c - 128)];
    bsw[idx] = f2bf(v);
}

// ---- build swizzled W_lin [256,40] padded to 48 cols ----
__global__ __launch_bounds__(256) void build_bswL(const float* __restrict__ Wlin,
                                                  unsigned short* __restrict__ bsw, int total) {
    int idx = blockIdx.x * 256 + threadIdx.x;  // 12288 total
    if (idx >= total) return;
    int t = idx;
    int j = t & 7; t >>= 3;
    int L = t & 63; t >>= 6;
    int ct = t % 3;
    int kt = t / 3;
    int k = kt * 32 + ((L >> 4) * 8) + j;
    int c = ct * 16 + (L & 15);
    float v = (c < 40) ? Wlin[k * 40 + c] : 0.f;
    bsw[idx] = f2bf(v);
}

// ================= CSR build (dst-bucketed), done once per launch =================

__global__ __launch_bounds__(256) void hist_deg(const int* __restrict__ dst,
                                                int* __restrict__ deg, int E) {
    int e = blockIdx.x * 256 + threadIdx.x;
    if (e >= E) return;
    atomicAdd(&deg[dst[e]], 1);
}

// per-block partial sums of deg
__global__ __launch_bounds__(256) void scan_partial(const int* __restrict__ deg,
                                                    int* __restrict__ partial, int N) {
    __shared__ int s[256];
    int t = threadIdx.x;
    int i = blockIdx.x * 256 + t;
    int v = (i < N) ? deg[i] : 0;
    s[t] = v; __syncthreads();
#pragma unroll
    for (int o = 1; o < 256; o <<= 1) {
        int x = (t >= o) ? s[t - o] : 0;
        __syncthreads();
        s[t] += x;
        __syncthreads();
    }
    if (t == 255) partial[blockIdx.x] = s[255];
}

// exclusive scan of block partials (single block, nb <= 512)
__global__ __launch_bounds__(512) void scan_block(int* __restrict__ partial, int nb) {
    __shared__ int s[512];
    int t = threadIdx.x;
    int v = (t < nb) ? partial[t] : 0;
    s[t] = v; __syncthreads();
#pragma unroll
    for (int o = 1; o < 512; o <<= 1) {
        int x = (t >= o) ? s[t - o] : 0;
        __syncthreads();
        s[t] += x;
        __syncthreads();
    }
    if (t < nb) partial[t] = s[t] - v;  // exclusive
}

// final: off[i] = exclusive scan, woff[i] = copy for slot allocation
__global__ __launch_bounds__(256) void scan_final(const int* __restrict__ deg,
                                                  const int* __restrict__ partial,
                                                  int* __restrict__ off_, int* __restrict__ woff,
                                                  int N) {
    __shared__ int s[256];
    int t = threadIdx.x;
    int i = blockIdx.x * 256 + t;
    int v = (i < N) ? deg[i] : 0;
    s[t] = v; __syncthreads();
#pragma unroll
    for (int o = 1; o < 256; o <<= 1) {
        int x = (t >= o) ? s[t - o] : 0;
        __syncthreads();
        s[t] += x;
        __syncthreads();
    }
    int excl = s[t] - v + partial[blockIdx.x];
    if (i < N) { off_[i] = excl; woff[i] = excl; }
}

__global__ __launch_bounds__(256) void csr_fill(const int* __restrict__ src,
                                                const int* __restrict__ dst,
                                                int* __restrict__ woff,
                                                int* __restrict__ csr_src, int E) {
    int e = blockIdx.x * 256 + threadIdx.x;
    if (e >= E) return;
    int p = atomicAdd(&woff[dst[e]], 1);
    csr_src[p] = src[e];
}

// ================= layer GEMM =================
// [N,128]bf16 @ [128,256]bf16 -> xr[N,128]bf16 (cols 0..127), acc[N,128]f32 = cols 128..255 + bias
__global__ __launch_bounds__(256) void gemm_layer(const unsigned short* __restrict__ Abf,
                                                  const unsigned short* __restrict__ Bsw,
                                                  const float* __restrict__ bias,
                                                  unsigned short* __restrict__ xr,
                                                  float* __restrict__ accbuf, int N) {
    int wid = blockIdx.x * 4 + (threadIdx.x >> 6);
    int L = threadIdx.x & 63;
    int r0 = wid * 16;
    if (r0 >= N) return;
    int arow = r0 + (L & 15);
    const bf16x8* Aptr = (const bf16x8*)(Abf + (size_t)arow * 128 + ((L >> 4) * 8));
    const bf16x8* Bptr = ((const bf16x8*)Bsw) + L;
    f32x4 acc[16];
#pragma unroll
    for (int i = 0; i < 16; i++) acc[i] = (f32x4){0.f, 0.f, 0.f, 0.f};
#pragma unroll
    for (int kt = 0; kt < 4; kt++) {
        bf16x8 a = Aptr[kt * 4];
#pragma unroll
        for (int ct = 0; ct < 16; ct++) {
            bf16x8 b = Bptr[(kt * 16 + ct) * 64];
            acc[ct] = __builtin_amdgcn_mfma_f32_16x16x32_bf16(a, b, acc[ct], 0, 0, 0);
        }
    }
    int rbase = r0 + (L >> 4) * 4;
    int cl = L & 15;
#pragma unroll
    for (int ct = 0; ct < 16; ct++) {
        int col = ct * 16 + cl;
#pragma unroll
        for (int r = 0; r < 4; r++) {
            int row = rbase + r;
            float v = acc[ct][r];
            if (col < 128)
                xr[(size_t)row * 128 + col] = f2bf(v);
            else
                accbuf[(size_t)row * 128 + (col - 128)] = v + bias[col - 128];
        }
    }
}

// ================= gather-aggregate + relu + bf16 convert =================
// one wave per node; lane L owns features 2L, 2L+1
__global__ __launch_bounds__(256) void agg_relu_cvt(const unsigned short* __restrict__ xr,
                                                    const float* __restrict__ acc,
                                                    const int* __restrict__ off_,
                                                    const int* __restrict__ deg,
                                                    const int* __restrict__ csr_src,
                                                    unsigned short* __restrict__ out, int N) {
    int node = blockIdx.x * 4 + (threadIdx.x >> 6);
    if (node >= N) return;
    int L = threadIdx.x & 63;
    int o = off_[node];
    int d = deg[node];
    float s0 = 0.f, s1 = 0.f;
    int k = 0;
    while (k < d) {
        int chunk = (d - k < 64) ? (d - k) : 64;
        int id = 0;
        if (L < chunk) id = csr_src[o + k + L];
#pragma unroll 4
        for (int j = 0; j < chunk; j++) {
            int s = __shfl(id, j, 64);
            unsigned int packed = *(const unsigned int*)(xr + (size_t)s * 128 + L * 2);
            s0 += bf2f((unsigned short)(packed & 0xFFFF));
            s1 += bf2f((unsigned short)(packed >> 16));
        }
        k += chunk;
    }
    float2 a = *(const float2*)(acc + (size_t)node * 128 + L * 2);
    float r0 = fmaxf(a.x + s0, 0.f);
    float r1 = fmaxf(a.y + s1, 0.f);
    unsigned int op = ((unsigned)f2bf(r1) << 16) | (unsigned)f2bf(r0);
    *(unsigned int*)(out + (size_t)node * 128 + L * 2) = op;
}

// ================= final GEMM + log_softmax =================
__global__ __launch_bounds__(256) void gemm_final(const unsigned short* __restrict__ x1bf,
                                                  const unsigned short* __restrict__ x2bf,
                                                  const unsigned short* __restrict__ Bsw,
                                                  const float* __restrict__ blin,
                                                  float* __restrict__ logits, int N) {
    int wid = blockIdx.x * 4 + (threadIdx.x >> 6);
    int L = threadIdx.x & 63;
    int r0 = wid * 16;
    if (r0 >= N) return;
    int arow = r0 + (L & 15);
    f32x4 acc[3];
#pragma unroll
    for (int i = 0; i < 3; i++) acc[i] = (f32x4){0.f, 0.f, 0.f, 0.f};
#pragma unroll
    for (int kt = 0; kt < 8; kt++) {
        const unsigned short* Ab = (kt < 4) ? x1bf : x2bf;
        int kk = (kt & 3) * 32 + ((L >> 4) * 8);
        bf16x8 a = *((const bf16x8*)(Ab + (size_t)arow * 128 + kk));
#pragma unroll
        for (int ct = 0; ct < 3; ct++) {
            bf16x8 b = ((const bf16x8*)Bsw)[(kt * 3 + ct) * 64 + L];
            acc[ct] = __builtin_amdgcn_mfma_f32_16x16x32_bf16(a, b, acc[ct], 0, 0, 0);
        }
    }
    int rbase = r0 + (L >> 4) * 4;
    int cl = L & 15;
#pragma unroll
    for (int ct = 0; ct < 3; ct++) {
        int col = ct * 16 + cl;
        if (col < 40) {
#pragma unroll
            for (int r = 0; r < 4; r++) {
                logits[(size_t)(rbase + r) * 40 + col] = acc[ct][r] + blin[col];
            }
        }
    }
}

__global__ __launch_bounds__(256) void log_softmax_k(const float* __restrict__ logits,
                                                     float* __restrict__ out, int N) {
    int node = blockIdx.x * 4 + (threadIdx.x >> 6);
    if (node >= N) return;
    int L = threadIdx.x & 63;
    float v = (L < 40) ? logits[(size_t)node * 40 + L] : -__builtin_inff();
    float m = v;
#pragma unroll
    for (int off = 32; off >= 1; off >>= 1) m = fmaxf(m, __shfl_xor(m, off, 64));
    float e = (L < 40) ? __expf(v - m) : 0.f;
    float s = e;
#pragma unroll
    for (int off = 32; off >= 1; off >>= 1) s += __shfl_xor(s, off, 64);
    if (L < 40) out[(size_t)node * 40 + L] = v - m - __logf(s);
}

extern "C" void kernel_launch(void* const* d_in, const int* in_sizes, int n_in,
                              void* d_out, int out_size, void* d_ws, size_t ws_size,
                              hipStream_t stream) {
    const float* x      = (const float*)d_in[0];
    const int*   edge   = (const int*)d_in[1];
    const float* Wrel1  = (const float*)d_in[2];
    const float* brel1  = (const float*)d_in[3];
    const float* Wroot1 = (const float*)d_in[4];
    const float* Wrel2  = (const float*)d_in[5];
    const float* brel2  = (const float*)d_in[6];
    const float* Wroot2 = (const float*)d_in[7];
    const float* Wlin   = (const float*)d_in[8];
    const float* blin   = (const float*)d_in[9];

    const int N = in_sizes[0] / 128;
    const int E = in_sizes[1] / 2;
    const int* src = edge;
    const int* dst = edge + E;

    char* ws = (char*)d_ws;
    size_t off = 0;
    auto alloc = [&](size_t bytes) -> void* {
        void* p = ws + off;
        off += (bytes + 255) & ~(size_t)255;
        return p;
    };
    unsigned short* xbf  = (unsigned short*)alloc((size_t)N * 128 * 2);  // reused as x2bf
    unsigned short* x1bf = (unsigned short*)alloc((size_t)N * 128 * 2);
    unsigned short* xr   = (unsigned short*)alloc((size_t)N * 128 * 2);
    float* acc1          = (float*)alloc((size_t)N * 128 * 4);           // reused as logits
    float* acc2          = (float*)alloc((size_t)N * 128 * 4);
    unsigned short* bsw1 = (unsigned short*)alloc(32768 * 2);
    unsigned short* bsw2 = (unsigned short*)alloc(32768 * 2);
    unsigned short* bswL = (unsigned short*)alloc(12288 * 2);
    int* deg     = (int*)alloc((size_t)N * 4);
    int* off_    = (int*)alloc((size_t)N * 4);
    int* woff    = (int*)alloc((size_t)N * 4);
    int* partial = (int*)alloc(512 * 4);
    int* csr_src = (int*)alloc((size_t)E * 4);
    unsigned short* x2bf = xbf;
    float* logits        = acc1;

    const int n4 = (N * 128) / 4;
    const int cvtBlocks = (n4 + 255) / 256;
    const int rowTiles = (N + 15) / 16;
    const int gemmBlocks = (rowTiles + 3) / 4;
    const int edgeBlocks = (E + 255) / 256;
    const int nb = (N + 255) / 256;   // 391 <= 512
    const int nodeBlocks = (N + 3) / 4;

    // weight swizzles + input convert
    build_bsw<<<128, 256, 0, stream>>>(Wrel1, Wroot1, bsw1);
    build_bsw<<<128, 256, 0, stream>>>(Wrel2, Wroot2, bsw2);
    build_bswL<<<48, 256, 0, stream>>>(Wlin, bswL, 12288);
    cvt_bf16<<<cvtBlocks, 256, 0, stream>>>(x, xbf, n4);

    // CSR build (once; shared by both layers)
    hipMemsetAsync(deg, 0, (size_t)N * 4, stream);
    hist_deg<<<edgeBlocks, 256, 0, stream>>>(dst, deg, E);
    scan_partial<<<nb, 256, 0, stream>>>(deg, partial, N);
    scan_block<<<1, 512, 0, stream>>>(partial, nb);
    scan_final<<<nb, 256, 0, stream>>>(deg, partial, off_, woff, N);
    csr_fill<<<edgeBlocks, 256, 0, stream>>>(src, dst, woff, csr_src, E);

    // layer 1
    gemm_layer<<<gemmBlocks, 256, 0, stream>>>(xbf, bsw1, brel1, xr, acc1, N);
    agg_relu_cvt<<<nodeBlocks, 256, 0, stream>>>(xr, acc1, off_, deg, csr_src, x1bf, N);

    // layer 2
    gemm_layer<<<gemmBlocks, 256, 0, stream>>>(x1bf, bsw2, brel2, xr, acc2, N);
    agg_relu_cvt<<<nodeBlocks, 256, 0, stream>>>(xr, acc2, off_, deg, csr_src, x2bf, N);

    // classifier + log_softmax
    gemm_final<<<gemmBlocks, 256, 0, stream>>>(x1bf, x2bf, bswL, blin, logits, N);
    log_softmax_k<<<nodeBlocks, 256, 0, stream>>>(logits, (float*)d_out, N);
}